// Round 10
// baseline (471.107 us; speedup 1.0000x reference)
//
#include <hip/hip_runtime.h>

#define NTOK  8192
#define NHEAD 16
#define DDIM  128
#define HDIM  384
#define NEXP  8

typedef __attribute__((ext_vector_type(8))) short short8;   // 8 x bf16 (4 VGPRs)
typedef __attribute__((ext_vector_type(4))) float f32x4;    // MFMA accumulator

// ---------------- workspace layout (bytes) ----------------
// wP: chunk-contiguous packed weights: [en(128)][chunk(12)][seg(24)][lane(64)][8]
//   seg 0..7  = W1  frags (kk = seg>>1, ctg = 2*chunk + (seg&1))
//   seg 8..15 = Wg  frags (same mapping)
//   seg 16..23= W2  frags (kk = chunk, ct = seg-16)
#define SZ_WP    (128UL*12*24*512*2)          // 37,748,736
#define OFF_WP   0UL
#define OFF_ROUT (OFF_WP + SZ_WP)             // Routing[8192], 16B each
#define OFF_CNT  (OFF_ROUT + 8192UL*16)       // cnt[16], cur[16]
#define OFF_LIST (OFF_CNT + 256)              // int[2][8192]
#define OFF_WL   (OFF_LIST + 2UL*8192*4)      // float[2][8192]
#define OFF_XG   (OFF_WL + 2UL*8192*4)        // bf16 gathered x panels
#define XG_SLOT  (16UL*8192*128*2)            // 33,554,432 per slot
#define XG_PAD   32768UL

struct Routing { int i0, i1; float w0, w1; };

__device__ __forceinline__ unsigned short f2bf(float f) {
  unsigned int u = __float_as_uint(f);
  u += 0x7fffu + ((u >> 16) & 1u);            // round-to-nearest-even
  return (unsigned short)(u >> 16);
}

// async global->LDS DMA, 16B per lane; LDS dest = uniform base + lane*16 (m104)
__device__ __forceinline__ void dma16(const unsigned short* g, char* l) {
  __builtin_amdgcn_global_load_lds(
      (const __attribute__((address_space(1))) unsigned int*)g,
      (__attribute__((address_space(3))) unsigned int*)l, 16, 0, 0);
}

// ---------------- weight conversion: fp32 -> bf16 chunk-contiguous frags ----------------
__global__ __launch_bounds__(256) void convA_kernel(
    const float* __restrict__ w1, const float* __restrict__ wg,
    unsigned short* __restrict__ wP) {
  __shared__ float ls[32][388];
  const int kk = blockIdx.x;          // 0..3
  const int en = blockIdx.y;          // 0..127
  const int z  = blockIdx.z;          // 0=W1, 1=Wg
  const float* src = (z == 0 ? w1 : wg) + ((size_t)en * DDIM + kk * 32) * HDIM;
  const int tid = threadIdx.x;
  #pragma unroll
  for (int i = 0; i < 12; ++i) {
    int f4 = i * 256 + tid;           // 3072 float4 = 32x384
    int row = f4 / 96, c4 = f4 % 96;
    float4 v = reinterpret_cast<const float4*>(src + (size_t)row * HDIM)[c4];
    ls[row][c4*4+0] = v.x; ls[row][c4*4+1] = v.y;
    ls[row][c4*4+2] = v.z; ls[row][c4*4+3] = v.w;
  }
  __syncthreads();
  #pragma unroll
  for (int i = 0; i < 6; ++i) {
    int fid = i * 256 + tid;          // 1536 = 24ct * 64lane
    int ct = fid >> 6, lane = fid & 63;
    int r0 = (lane >> 4) * 8, c = ct * 16 + (lane & 15);
    unsigned short o[8];
    #pragma unroll
    for (int j = 0; j < 8; ++j) o[j] = f2bf(ls[r0 + j][c]);
    size_t off = (((size_t)en * 12 + (ct >> 1)) * 24 + (z * 8 + kk * 2 + (ct & 1))) * 512
               + (size_t)lane * 8;
    reinterpret_cast<uint4*>(wP + off)[0] =
        make_uint4((unsigned)o[0] | ((unsigned)o[1] << 16),
                   (unsigned)o[2] | ((unsigned)o[3] << 16),
                   (unsigned)o[4] | ((unsigned)o[5] << 16),
                   (unsigned)o[6] | ((unsigned)o[7] << 16));
  }
}

__global__ __launch_bounds__(256) void convB_kernel(
    const float* __restrict__ w2, unsigned short* __restrict__ wP) {
  __shared__ float ls[32][132];
  const int kk = blockIdx.x;          // 0..11 (= chunk)
  const int en = blockIdx.y;
  const float* src = w2 + ((size_t)en * HDIM + kk * 32) * DDIM;
  const int tid = threadIdx.x;
  #pragma unroll
  for (int i = 0; i < 4; ++i) {
    int f4 = i * 256 + tid;           // 1024 float4 = 32x128
    int row = f4 >> 5, c4 = f4 & 31;
    float4 v = reinterpret_cast<const float4*>(src + (size_t)row * DDIM)[c4];
    ls[row][c4*4+0] = v.x; ls[row][c4*4+1] = v.y;
    ls[row][c4*4+2] = v.z; ls[row][c4*4+3] = v.w;
  }
  __syncthreads();
  #pragma unroll
  for (int i = 0; i < 2; ++i) {
    int fid = i * 256 + tid;          // 512 = 8ct * 64lane
    int ct = fid >> 6, lane = fid & 63;
    int r0 = (lane >> 4) * 8, c = ct * 16 + (lane & 15);
    unsigned short o[8];
    #pragma unroll
    for (int j = 0; j < 8; ++j) o[j] = f2bf(ls[r0 + j][c]);
    size_t off = (((size_t)en * 12 + kk) * 24 + (16 + ct)) * 512 + (size_t)lane * 8;
    reinterpret_cast<uint4*>(wP + off)[0] =
        make_uint4((unsigned)o[0] | ((unsigned)o[1] << 16),
                   (unsigned)o[2] | ((unsigned)o[3] << 16),
                   (unsigned)o[4] | ((unsigned)o[5] << 16),
                   (unsigned)o[6] | ((unsigned)o[7] << 16));
  }
}

// ---------------- router: no LDS, no atomics, 1 wave = 4 tokens ----------------
__global__ __launch_bounds__(256) void router_kernel(
    const float* __restrict__ x, const float* __restrict__ rw,
    Routing* __restrict__ routing) {
  const int lane = threadIdx.x & 63;
  const int wgid = blockIdx.x * 4 + (threadIdx.x >> 6);
  const int tok0 = wgid * 4;
  float acc[4][8];
  #pragma unroll
  for (int t = 0; t < 4; ++t)
    #pragma unroll
    for (int e = 0; e < 8; ++e) acc[t][e] = 0.f;
  const float4* xr = reinterpret_cast<const float4*>(x);
  const float4* wr = reinterpret_cast<const float4*>(rw);
  #pragma unroll
  for (int c = 0; c < 8; ++c) {
    float4 wv[8];
    #pragma unroll
    for (int e = 0; e < 8; ++e) wv[e] = wr[e * 512 + c * 64 + lane];
    #pragma unroll
    for (int t = 0; t < 4; ++t) {
      float4 xv = xr[(size_t)(tok0 + t) * 512 + c * 64 + lane];
      #pragma unroll
      for (int e = 0; e < 8; ++e)
        acc[t][e] += xv.x * wv[e].x + xv.y * wv[e].y + xv.z * wv[e].z + xv.w * wv[e].w;
    }
  }
  #pragma unroll
  for (int t = 0; t < 4; ++t)
    #pragma unroll
    for (int e = 0; e < 8; ++e) {
      acc[t][e] += __shfl_xor(acc[t][e], 1);
      acc[t][e] += __shfl_xor(acc[t][e], 2);
      acc[t][e] += __shfl_xor(acc[t][e], 4);
    }
  const int l3 = lane & 7;
  #pragma unroll
  for (int t = 0; t < 4; ++t) {
    float v0 = (l3 & 1) ? acc[t][1] : acc[t][0];
    float v1 = (l3 & 1) ? acc[t][3] : acc[t][2];
    float v2 = (l3 & 1) ? acc[t][5] : acc[t][4];
    float v3 = (l3 & 1) ? acc[t][7] : acc[t][6];
    float u0 = (l3 & 2) ? v1 : v0;
    float u1 = (l3 & 2) ? v3 : v2;
    float sel = (l3 & 4) ? u1 : u0;
    sel += __shfl_xor(sel, 8);
    sel += __shfl_xor(sel, 16);
    sel += __shfl_xor(sel, 32);
    float le[8];
    #pragma unroll
    for (int e = 0; e < 8; ++e) le[e] = __shfl(sel, e);
    if (lane == 0) {
      int tok = tok0 + t;
      int i0 = 0; float m0 = le[0];
      #pragma unroll
      for (int e = 1; e < 8; ++e) if (le[e] > m0) { m0 = le[e]; i0 = e; }
      int i1 = -1; float m1 = -3.4e38f;
      #pragma unroll
      for (int e = 0; e < 8; ++e) if (e != i0 && le[e] > m1) { m1 = le[e]; i1 = e; }
      float ed = __expf(m1 - m0);
      Routing r; r.i0 = i0; r.i1 = i1;
      r.w0 = 1.f / (1.f + ed); r.w1 = ed / (1.f + ed);
      routing[tok] = r;
    }
  }
}

// ---------------- count: one block per (slot,expert), atomic-free ----------------
__global__ __launch_bounds__(256) void count_kernel(
    const Routing* __restrict__ routing, int* __restrict__ cnt) {
  const int s = blockIdx.x >> 3, e = blockIdx.x & 7;
  const int tid = threadIdx.x;
  int c = 0;
  for (int t = tid; t < NTOK; t += 256) {
    Routing r = routing[t];
    c += ((s == 0 ? r.i0 : r.i1) == e);
  }
  c += __shfl_xor(c, 32); c += __shfl_xor(c, 16); c += __shfl_xor(c, 8);
  c += __shfl_xor(c, 4);  c += __shfl_xor(c, 2);  c += __shfl_xor(c, 1);
  __shared__ int wsum[4];
  if ((tid & 63) == 0) wsum[tid >> 6] = c;
  __syncthreads();
  if (tid == 0) cnt[blockIdx.x] = wsum[0] + wsum[1] + wsum[2] + wsum[3];
}

// ---------------- build: per-slot prefix offsets ----------------
__global__ void build_kernel(const int* __restrict__ cnt, int* __restrict__ cur) {
  int tid = threadIdx.x;
  if (tid < 16) {
    int s = tid >> 3, e = tid & 7;
    int b = 0;
    for (int k = 0; k < e; ++k) b += cnt[s * 8 + k];
    cur[tid] = b;
  }
}

// ---------------- compact: ordered, atomic-free scatter via block scan ----------------
__global__ __launch_bounds__(256) void compact_kernel(
    const Routing* __restrict__ routing, const int* __restrict__ cur,
    int* __restrict__ list, float* __restrict__ wl) {
  const int s = blockIdx.x >> 3, e = blockIdx.x & 7;
  const int tid = threadIdx.x;
  __shared__ int ps[256];
  int myc = 0;
  for (int t = tid; t < NTOK; t += 256) {
    Routing r = routing[t];
    myc += ((s == 0 ? r.i0 : r.i1) == e);
  }
  ps[tid] = myc;
  __syncthreads();
  for (int off = 1; off < 256; off <<= 1) {
    int v = (tid >= off) ? ps[tid - off] : 0;
    __syncthreads();
    ps[tid] += v;
    __syncthreads();
  }
  int base = cur[blockIdx.x] + ps[tid] - myc;
  for (int t = tid; t < NTOK; t += 256) {
    Routing r = routing[t];
    int ei = (s == 0 ? r.i0 : r.i1);
    if (ei == e) {
      list[s * NTOK + base] = t;
      wl[s * NTOK + base] = (s == 0 ? r.w0 : r.w1);
      ++base;
    }
  }
}

// ---------------- gather: x fp32 -> bf16 panels [n][pos][128], pre-swizzled ----------------
// Per slot: pos-ordered (expert-contiguous) head-major panels; 16B block j of a
// row is stored at j ^ (pos&7) so the expert's linear DMA + XOR ds_read is
// bank-conflict-free. Reads are 8KB-contiguous per token; writes 256B rows.
__global__ __launch_bounds__(256) void gather_kernel(
    const float* __restrict__ x, const int* __restrict__ list,
    unsigned short* __restrict__ xg, const int slot) {
  const int tid = threadIdx.x;
  const int n = tid >> 4, j = tid & 15;
  for (int it = 0; it < 64; ++it) {
    int pos = blockIdx.x * 64 + it;
    int t = list[slot * NTOK + pos];
    const float* src = x + ((size_t)t * NHEAD + n) * DDIM + j * 8;
    float4 v0 = reinterpret_cast<const float4*>(src)[0];
    float4 v1 = reinterpret_cast<const float4*>(src)[1];
    uint4 w = make_uint4(
        (unsigned)f2bf(v0.x) | ((unsigned)f2bf(v0.y) << 16),
        (unsigned)f2bf(v0.z) | ((unsigned)f2bf(v0.w) << 16),
        (unsigned)f2bf(v1.x) | ((unsigned)f2bf(v1.y) << 16),
        (unsigned)f2bf(v1.z) | ((unsigned)f2bf(v1.w) << 16));
    *reinterpret_cast<uint4*>(xg + ((size_t)n * NTOK + pos) * 128 + (size_t)((j ^ (pos & 7)) * 8)) = w;
  }
}

// ---------------- expert: weight-stationary, x streaming ----------------
// 2 blocks per (e,n): block parity kpar takes tiles kpar, kpar+2, ... of that
// expert's token list. 8 waves; wave holds W1/Wg (3 ctg x 4 kk) + W2 (12 kk x
// its d-ct) in 144 VGPRs for the WHOLE kernel -- zero weight traffic in the
// tile loop. Per 128-token tile: DMA 32KB x (hidden under prev stage2) ->
// stage1 (192 MFMA/wave, silu, P[128][384] in LDS) -> barrier -> stage2
// (96 MFMA/wave vs reg W2) + store -> barrier. 2 barriers/tile.
// LDS: x 32KB + P 128x772B = 131,584B -> 1 block/CU by design.
__global__ __launch_bounds__(512, 2) void expert_kernel(
    const unsigned short* __restrict__ xg,
    const unsigned short* __restrict__ wP,
    const int* __restrict__ list, const float* __restrict__ wl,
    const int* __restrict__ cnt,
    float* __restrict__ out, const int slot)
{
  extern __shared__ char smem[];
  char* xls = smem;            // 128 rows x 256B, XOR-swizzled by ((ebase+row)&7)<<4
  char* P   = smem + 32768;    // 128 rows x 772B (384 bf16 + 4B pad)
  const int bid = blockIdx.x;
  const int e = bid >> 5, n = (bid >> 1) & 15, kpar = bid & 1;
  const int cntE  = cnt[slot * 8 + e];
  const int ebase = cnt[16 + slot * 8 + e];   // cur[] lives at cnt+16
  const int ntiles = (cntE + 127) >> 7;
  if (kpar >= ntiles) return;
  const int tid = threadIdx.x;
  const int wid = tid >> 6, lane = tid & 63;
  const int lr = lane & 15, lq = lane >> 4;
  const f32x4 z4 = {0.f, 0.f, 0.f, 0.f};

  // ---- load this wave's weight slices into registers (stay for whole kernel) ----
  const unsigned short* wsrc = wP + (size_t)(e * NHEAD + n) * (12 * 24 * 512);
  short8 w1r[3][4], wgr[3][4], w2r[12];
  #pragma unroll
  for (int c = 0; c < 3; ++c) {
    const int ctg = wid * 3 + c;
    #pragma unroll
    for (int kk = 0; kk < 4; ++kk) {
      size_t off = ((size_t)(ctg >> 1) * 24 + (kk * 2 + (ctg & 1))) * 512 + (size_t)lane * 8;
      w1r[c][kk] = *reinterpret_cast<const short8*>(wsrc + off);
      wgr[c][kk] = *reinterpret_cast<const short8*>(wsrc + off + 8 * 512);
    }
  }
  #pragma unroll
  for (int kk = 0; kk < 12; ++kk)
    w2r[kk] = *reinterpret_cast<const short8*>(
        wsrc + ((size_t)kk * 24 + 16 + wid) * 512 + (size_t)lane * 8);

  const unsigned short* xbase = xg + ((size_t)n * NTOK + ebase) * 128;

  // prologue: DMA tile kpar's x (32KB; 4KB per wave)
  {
    const unsigned short* src = xbase + (size_t)kpar * 128 * 128 + wid * 2048;
    #pragma unroll
    for (int i = 0; i < 4; ++i)
      dma16(src + i * 512 + lane * 8, xls + wid * 4096 + i * 1024);
  }
  asm volatile("s_waitcnt vmcnt(0)" ::: "memory");
  __builtin_amdgcn_s_barrier();

  for (int t = kpar; t < ntiles; t += 2) {
    // ---- stage 1: P[128][384] = (x@W1)*silu(x@Wg), weights from regs ----
    #pragma unroll 2
    for (int mi = 0; mi < 8; ++mi) {
      const int row = mi * 16 + lr;
      const int key = ((ebase + row) & 7) << 4;
      short8 a[4];
      #pragma unroll
      for (int kk = 0; kk < 4; ++kk)
        a[kk] = *reinterpret_cast<const short8*>(xls + row * 256 + ((kk * 64 + lq * 16) ^ key));
      #pragma unroll
      for (int c = 0; c < 3; ++c) {
        f32x4 ah = z4, ag = z4;
        #pragma unroll
        for (int kk = 0; kk < 4; ++kk) {
          ah = __builtin_amdgcn_mfma_f32_16x16x32_bf16(a[kk], w1r[c][kk], ah, 0, 0, 0);
          ag = __builtin_amdgcn_mfma_f32_16x16x32_bf16(a[kk], wgr[c][kk], ag, 0, 0, 0);
        }
        const int pcol = (wid * 3 + c) * 16 + lr;
        #pragma unroll
        for (int r = 0; r < 4; ++r) {
          float h1 = ah[r], g = ag[r];
          float val = h1 * g * __builtin_amdgcn_rcpf(1.f + __expf(-g));  // silu
          int prow = mi * 16 + lq * 4 + r;
          *reinterpret_cast<unsigned short*>(P + prow * 772 + pcol * 2) = f2bf(val);
        }
      }
    }
    asm volatile("s_waitcnt lgkmcnt(0)" ::: "memory");
    __builtin_amdgcn_s_barrier();

    // DMA next tile's x (overwrites xls; nobody reads x during stage 2)
    if (t + 2 < ntiles) {
      const unsigned short* src = xbase + (size_t)(t + 2) * 128 * 128 + wid * 2048;
      #pragma unroll
      for (int i = 0; i < 4; ++i)
        dma16(src + i * 512 + lane * 8, xls + wid * 4096 + i * 1024);
    }

    // ---- stage 2: out = P @ W2 (wave's 16 d-cols), W2 from regs; store ----
    #pragma unroll 2
    for (int mi = 0; mi < 8; ++mi) {
      f32x4 acc = z4;
      #pragma unroll
      for (int kk = 0; kk < 12; ++kk) {
        short8 p = *reinterpret_cast<const short8*>(P + (mi * 16 + lr) * 772 + kk * 64 + lq * 16);
        acc = __builtin_amdgcn_mfma_f32_16x16x32_bf16(p, w2r[kk], acc, 0, 0, 0);
      }
      #pragma unroll
      for (int r = 0; r < 4; ++r) {
        int grow = t * 128 + mi * 16 + lq * 4 + r;
        if (grow < cntE) {
          int tok = list[slot * NTOK + ebase + grow];
          float wt = wl[slot * NTOK + ebase + grow];
          float* op = out + ((size_t)tok * NHEAD + n) * DDIM + wid * 16 + lr;
          float v = acc[r] * wt;
          if (slot == 0) *op = v;     // pass 0: every (tok,head) exactly once
          else           *op += v;    // pass 1: unique writer, after pass 0
        }
      }
    }
    asm volatile("s_waitcnt vmcnt(0)" ::: "memory");  // next x landed
    __builtin_amdgcn_s_barrier();
  }
}

extern "C" void kernel_launch(void* const* d_in, const int* in_sizes, int n_in,
                              void* d_out, int out_size, void* d_ws, size_t ws_size,
                              hipStream_t stream) {
  const float* x  = (const float*)d_in[0];
  const float* rw = (const float*)d_in[1];
  const float* w1 = (const float*)d_in[2];
  const float* wg = (const float*)d_in[3];
  const float* w2 = (const float*)d_in[4];
  float* out = (float*)d_out;
  char* ws = (char*)d_ws;

  unsigned short* wP = (unsigned short*)(ws + OFF_WP);
  Routing* routing = (Routing*)(ws + OFF_ROUT);
  int* cnt = (int*)(ws + OFF_CNT);
  int* cur = cnt + 16;
  int* list = (int*)(ws + OFF_LIST);
  float* wl = (float*)(ws + OFF_WL);
  unsigned short* xg0 = (unsigned short*)(ws + OFF_XG);

  const size_t need2 = OFF_XG + 2 * XG_SLOT + XG_PAD;
  const bool dual = (ws_size >= need2);
  unsigned short* xg1 = dual ? (unsigned short*)(ws + OFF_XG + XG_SLOT) : xg0;

  convA_kernel<<<dim3(4, 128, 2), 256, 0, stream>>>(w1, wg, wP);
  convB_kernel<<<dim3(12, 128, 1), 256, 0, stream>>>(w2, wP);
  router_kernel<<<512, 256, 0, stream>>>(x, rw, routing);
  count_kernel<<<16, 256, 0, stream>>>(routing, cnt);
  build_kernel<<<1, 64, 0, stream>>>(cnt, cur);
  compact_kernel<<<16, 256, 0, stream>>>(routing, cur, list, wl);

  if (dual) {
    gather_kernel<<<128, 256, 0, stream>>>(x, list, xg0, 0);
    gather_kernel<<<128, 256, 0, stream>>>(x, list, xg1, 1);
    expert_kernel<<<256, 512, 131584, stream>>>(xg0, wP, list, wl, cnt, out, 0);
    expert_kernel<<<256, 512, 131584, stream>>>(xg1, wP, list, wl, cnt, out, 1);
  } else {
    gather_kernel<<<128, 256, 0, stream>>>(x, list, xg0, 0);
    expert_kernel<<<256, 512, 131584, stream>>>(xg0, wP, list, wl, cnt, out, 0);
    gather_kernel<<<128, 256, 0, stream>>>(x, list, xg0, 1);
    expert_kernel<<<256, 512, 131584, stream>>>(xg0, wP, list, wl, cnt, out, 1);
  }
}

// Round 11
// 296.718 us; speedup vs baseline: 1.5877x; 1.5877x over previous
//
#include <hip/hip_runtime.h>

#define NTOK  8192
#define NHEAD 16
#define DDIM  128
#define HDIM  384
#define NEXP  8
#define TILE  128
#define PADN  9216     // per-slot padded list length (128-aligned expert segments)
#define ENTRIES 1280   // per-slot work entries; worst lid = 7 + 8*142 = 1143

typedef __attribute__((ext_vector_type(8))) short short8;   // 8 x bf16 (4 VGPRs)
typedef __attribute__((ext_vector_type(4))) float f32x4;    // MFMA accumulator

// ---------------- workspace layout (bytes) ----------------
// wP: chunk-contiguous packed weights: [en(128)][chunk(12)][seg(24)][lane(64)][8]
//   seg 0..7 = W1 (kk=seg>>1, ctg=2*chunk+(seg&1)); 8..15 = Wg; 16..23 = W2 (kk=chunk, ct=seg-16)
#define SZ_WP    (128UL*12*24*512*2)          // 37,748,736
#define OFF_WP   0UL
#define OFF_ROUT (OFF_WP + SZ_WP)             // Routing[8192], 16B each
#define OFF_CNT  (OFF_ROUT + 8192UL*16)       // cnt[16], cur[16]
#define OFF_TAB  (OFF_CNT + 256)              // int4[2][ENTRIES]
#define OFF_LIST (OFF_TAB + 2UL*ENTRIES*16)   // int[2][PADN]
#define OFF_POS  (OFF_LIST + 2UL*PADN*4)      // int[2][NTOK]
#define OFF_WL   (OFF_POS + 2UL*NTOK*4)       // float[2][PADN]
#define OFF_XG   (OFF_WL + 2UL*PADN*4)        // bf16 panels [slot][n][PADN][128]
#define XG_SLOT  (16UL*PADN*128*2)            // 37,748,736 per slot

struct Routing { int i0, i1; float w0, w1; };

__device__ __forceinline__ unsigned short f2bf(float f) {
  unsigned int u = __float_as_uint(f);
  u += 0x7fffu + ((u >> 16) & 1u);            // round-to-nearest-even
  return (unsigned short)(u >> 16);
}

// async global->LDS DMA, 16B per lane; LDS dest = uniform base + lane*16 (m104)
__device__ __forceinline__ void dma16(const unsigned short* g, char* l) {
  __builtin_amdgcn_global_load_lds(
      (const __attribute__((address_space(1))) unsigned int*)g,
      (__attribute__((address_space(3))) unsigned int*)l, 16, 0, 0);
}

// ---------------- weight conversion: fp32 -> bf16 chunk-contiguous frags ----------------
__global__ __launch_bounds__(256) void convA_kernel(
    const float* __restrict__ w1, const float* __restrict__ wg,
    unsigned short* __restrict__ wP) {
  __shared__ float ls[32][388];
  const int kk = blockIdx.x;          // 0..3
  const int en = blockIdx.y;          // 0..127
  const int z  = blockIdx.z;          // 0=W1, 1=Wg
  const float* src = (z == 0 ? w1 : wg) + ((size_t)en * DDIM + kk * 32) * HDIM;
  const int tid = threadIdx.x;
  #pragma unroll
  for (int i = 0; i < 12; ++i) {
    int f4 = i * 256 + tid;           // 3072 float4 = 32x384
    int row = f4 / 96, c4 = f4 % 96;
    float4 v = reinterpret_cast<const float4*>(src + (size_t)row * HDIM)[c4];
    ls[row][c4*4+0] = v.x; ls[row][c4*4+1] = v.y;
    ls[row][c4*4+2] = v.z; ls[row][c4*4+3] = v.w;
  }
  __syncthreads();
  #pragma unroll
  for (int i = 0; i < 6; ++i) {
    int fid = i * 256 + tid;          // 1536 = 24ct * 64lane
    int ct = fid >> 6, lane = fid & 63;
    int r0 = (lane >> 4) * 8, c = ct * 16 + (lane & 15);
    unsigned short o[8];
    #pragma unroll
    for (int j = 0; j < 8; ++j) o[j] = f2bf(ls[r0 + j][c]);
    size_t off = (((size_t)en * 12 + (ct >> 1)) * 24 + (z * 8 + kk * 2 + (ct & 1))) * 512
               + (size_t)lane * 8;
    reinterpret_cast<uint4*>(wP + off)[0] =
        make_uint4((unsigned)o[0] | ((unsigned)o[1] << 16),
                   (unsigned)o[2] | ((unsigned)o[3] << 16),
                   (unsigned)o[4] | ((unsigned)o[5] << 16),
                   (unsigned)o[6] | ((unsigned)o[7] << 16));
  }
}

__global__ __launch_bounds__(256) void convB_kernel(
    const float* __restrict__ w2, unsigned short* __restrict__ wP) {
  __shared__ float ls[32][132];
  const int kk = blockIdx.x;          // 0..11 (= chunk)
  const int en = blockIdx.y;
  const float* src = w2 + ((size_t)en * HDIM + kk * 32) * DDIM;
  const int tid = threadIdx.x;
  #pragma unroll
  for (int i = 0; i < 4; ++i) {
    int f4 = i * 256 + tid;           // 1024 float4 = 32x128
    int row = f4 >> 5, c4 = f4 & 31;
    float4 v = reinterpret_cast<const float4*>(src + (size_t)row * DDIM)[c4];
    ls[row][c4*4+0] = v.x; ls[row][c4*4+1] = v.y;
    ls[row][c4*4+2] = v.z; ls[row][c4*4+3] = v.w;
  }
  __syncthreads();
  #pragma unroll
  for (int i = 0; i < 2; ++i) {
    int fid = i * 256 + tid;          // 512 = 8ct * 64lane
    int ct = fid >> 6, lane = fid & 63;
    int r0 = (lane >> 4) * 8, c = ct * 16 + (lane & 15);
    unsigned short o[8];
    #pragma unroll
    for (int j = 0; j < 8; ++j) o[j] = f2bf(ls[r0 + j][c]);
    size_t off = (((size_t)en * 12 + kk) * 24 + (16 + ct)) * 512 + (size_t)lane * 8;
    reinterpret_cast<uint4*>(wP + off)[0] =
        make_uint4((unsigned)o[0] | ((unsigned)o[1] << 16),
                   (unsigned)o[2] | ((unsigned)o[3] << 16),
                   (unsigned)o[4] | ((unsigned)o[5] << 16),
                   (unsigned)o[6] | ((unsigned)o[7] << 16));
  }
}

// ---------------- router: no LDS, no atomics, 1 wave = 4 tokens ----------------
__global__ __launch_bounds__(256) void router_kernel(
    const float* __restrict__ x, const float* __restrict__ rw,
    Routing* __restrict__ routing) {
  const int lane = threadIdx.x & 63;
  const int wgid = blockIdx.x * 4 + (threadIdx.x >> 6);
  const int tok0 = wgid * 4;
  float acc[4][8];
  #pragma unroll
  for (int t = 0; t < 4; ++t)
    #pragma unroll
    for (int e = 0; e < 8; ++e) acc[t][e] = 0.f;
  const float4* xr = reinterpret_cast<const float4*>(x);
  const float4* wr = reinterpret_cast<const float4*>(rw);
  #pragma unroll
  for (int c = 0; c < 8; ++c) {
    float4 wv[8];
    #pragma unroll
    for (int e = 0; e < 8; ++e) wv[e] = wr[e * 512 + c * 64 + lane];
    #pragma unroll
    for (int t = 0; t < 4; ++t) {
      float4 xv = xr[(size_t)(tok0 + t) * 512 + c * 64 + lane];
      #pragma unroll
      for (int e = 0; e < 8; ++e)
        acc[t][e] += xv.x * wv[e].x + xv.y * wv[e].y + xv.z * wv[e].z + xv.w * wv[e].w;
    }
  }
  #pragma unroll
  for (int t = 0; t < 4; ++t)
    #pragma unroll
    for (int e = 0; e < 8; ++e) {
      acc[t][e] += __shfl_xor(acc[t][e], 1);
      acc[t][e] += __shfl_xor(acc[t][e], 2);
      acc[t][e] += __shfl_xor(acc[t][e], 4);
    }
  const int l3 = lane & 7;
  #pragma unroll
  for (int t = 0; t < 4; ++t) {
    float v0 = (l3 & 1) ? acc[t][1] : acc[t][0];
    float v1 = (l3 & 1) ? acc[t][3] : acc[t][2];
    float v2 = (l3 & 1) ? acc[t][5] : acc[t][4];
    float v3 = (l3 & 1) ? acc[t][7] : acc[t][6];
    float u0 = (l3 & 2) ? v1 : v0;
    float u1 = (l3 & 2) ? v3 : v2;
    float sel = (l3 & 4) ? u1 : u0;
    sel += __shfl_xor(sel, 8);
    sel += __shfl_xor(sel, 16);
    sel += __shfl_xor(sel, 32);
    float le[8];
    #pragma unroll
    for (int e = 0; e < 8; ++e) le[e] = __shfl(sel, e);
    if (lane == 0) {
      int tok = tok0 + t;
      int i0 = 0; float m0 = le[0];
      #pragma unroll
      for (int e = 1; e < 8; ++e) if (le[e] > m0) { m0 = le[e]; i0 = e; }
      int i1 = -1; float m1 = -3.4e38f;
      #pragma unroll
      for (int e = 0; e < 8; ++e) if (e != i0 && le[e] > m1) { m1 = le[e]; i1 = e; }
      float ed = __expf(m1 - m0);
      Routing r; r.i0 = i0; r.i1 = i1;
      r.w0 = 1.f / (1.f + ed); r.w1 = ed / (1.f + ed);
      routing[tok] = r;
    }
  }
}

// ---------------- count: one block per (slot,expert), atomic-free ----------------
__global__ __launch_bounds__(256) void count_kernel(
    const Routing* __restrict__ routing, int* __restrict__ cnt) {
  const int s = blockIdx.x >> 3, e = blockIdx.x & 7;
  const int tid = threadIdx.x;
  int c = 0;
  for (int t = tid; t < NTOK; t += 256) {
    Routing r = routing[t];
    c += ((s == 0 ? r.i0 : r.i1) == e);
  }
  c += __shfl_xor(c, 32); c += __shfl_xor(c, 16); c += __shfl_xor(c, 8);
  c += __shfl_xor(c, 4);  c += __shfl_xor(c, 2);  c += __shfl_xor(c, 1);
  __shared__ int wsum[4];
  if ((tid & 63) == 0) wsum[tid >> 6] = c;
  __syncthreads();
  if (tid == 0) cnt[blockIdx.x] = wsum[0] + wsum[1] + wsum[2] + wsum[3];
}

// ---------------- build: 128-aligned prefix offsets, -1 list init, work table ----------------
__global__ void build_kernel(const int* __restrict__ cnt, int* __restrict__ cur,
                             int4* __restrict__ table, int* __restrict__ list) {
  const int tid = threadIdx.x;
  for (int i = tid; i < 2 * ENTRIES; i += 256)
    table[i] = make_int4(0, 0, 0, 0);          // rcnt==0 sentinel -> early exit
  for (int i = tid; i < 2 * PADN; i += 256)
    list[i] = -1;                               // padded slots
  __syncthreads();
  if (tid < 16) {                               // 128-aligned per-expert bases
    int s = tid >> 3, e = tid & 7;
    int b = 0;
    for (int k = 0; k < e; ++k) b += ((cnt[s * 8 + k] + 127) >> 7) << 7;
    cur[tid] = b;
  }
  __syncthreads();
  if (tid < 16) {                               // one thread per (slot, xcd)
    int s = tid >> 3, xcd = tid & 7;
    int j = 0, ab = 0;
    for (int e = 0; e < 8; ++e) {
      int c = cnt[s * 8 + e];
      #pragma unroll
      for (int nn = 0; nn < 2; ++nn) {
        int n = xcd + nn * 8;                   // heads with n%8 == xcd
        for (int t = 0; t < c; t += TILE) {
          int rc = c - t; if (rc > TILE) rc = TILE;
          table[s * ENTRIES + xcd + 8 * j] = make_int4(e, ab + t, rc, n);
          ++j;
        }
      }
      ab += ((c + 127) >> 7) << 7;
    }
  }
}

// ---------------- compact: ordered atomic-free scatter + inverse pos map ----------------
__global__ __launch_bounds__(256) void compact_kernel(
    const Routing* __restrict__ routing, const int* __restrict__ cur,
    int* __restrict__ list, float* __restrict__ wl, int* __restrict__ posmap) {
  const int s = blockIdx.x >> 3, e = blockIdx.x & 7;
  const int tid = threadIdx.x;
  __shared__ int ps[256];
  int myc = 0;
  for (int t = tid; t < NTOK; t += 256) {
    Routing r = routing[t];
    myc += ((s == 0 ? r.i0 : r.i1) == e);
  }
  ps[tid] = myc;
  __syncthreads();
  for (int off = 1; off < 256; off <<= 1) {
    int v = (tid >= off) ? ps[tid - off] : 0;
    __syncthreads();
    ps[tid] += v;
    __syncthreads();
  }
  int base = cur[blockIdx.x] + ps[tid] - myc;   // aligned base + exclusive prefix
  for (int t = tid; t < NTOK; t += 256) {
    Routing r = routing[t];
    int ei = (s == 0 ? r.i0 : r.i1);
    if (ei == e) {
      list[s * PADN + base] = t;
      wl[s * PADN + base] = (s == 0 ? r.w0 : r.w1);
      posmap[s * NTOK + t] = base;
      ++base;
    }
  }
}

// ---------------- gather: x fp32 -> bf16 panels, single pass, both slots ----------------
// Panel: xg[s][n][pos][128 bf16], pos in padded domain; 16B block j of a row
// stored at j ^ (pos&7) so the expert's linear DMA + XOR ds_read is
// conflict-free. Reads 8KB-contiguous per token (all 16 heads), x read ONCE.
// mode: 0 = both slots, 1 = slot0 only, 2 = slot1 only (ws fallback).
__global__ __launch_bounds__(256) void gather_kernel(
    const float* __restrict__ x, const int* __restrict__ posmap,
    unsigned short* __restrict__ xg0, unsigned short* __restrict__ xg1,
    const int mode) {
  const int tid = threadIdx.x;
  const int n = tid >> 4, j = tid & 15;
  for (int it = 0; it < 32; ++it) {
    int t = blockIdx.x * 32 + it;
    const float* src = x + ((size_t)t * NHEAD + n) * DDIM + j * 8;
    float4 v0 = reinterpret_cast<const float4*>(src)[0];
    float4 v1 = reinterpret_cast<const float4*>(src)[1];
    uint4 w = make_uint4(
        (unsigned)f2bf(v0.x) | ((unsigned)f2bf(v0.y) << 16),
        (unsigned)f2bf(v0.z) | ((unsigned)f2bf(v0.w) << 16),
        (unsigned)f2bf(v1.x) | ((unsigned)f2bf(v1.y) << 16),
        (unsigned)f2bf(v1.z) | ((unsigned)f2bf(v1.w) << 16));
    if (mode != 2) {
      int p0 = posmap[t];
      *reinterpret_cast<uint4*>(xg0 + ((size_t)n * PADN + p0) * 128 + ((j ^ (p0 & 7)) * 8)) = w;
    }
    if (mode != 1) {
      int p1 = posmap[NTOK + t];
      *reinterpret_cast<uint4*>(xg1 + ((size_t)n * PADN + p1) * 128 + ((j ^ (p1 & 7)) * 8)) = w;
    }
  }
}

// ---------------- fused expert: 128-token tile, 8 waves, all-DMA pipeline ----------------
// Identical to the R9 skeleton (0 bank conflicts, VGPR~64) except x now arrives
// as ONE contiguous 32KB DMA from the pre-gathered bf16 panel (L3-hot) instead
// of ~70MB/dispatch of scattered 512B HBM reads -- R9's measured wall
// (FETCH 86MB @ 788GB/s = the whole 111us). Weight chunks: counted vmcnt(3),
// chunk c+1 always in flight. LDS: 48K wbuf (reused for x staging) + 4x2304B P.
__global__ __launch_bounds__(512, 2) void expert_kernel(
    const unsigned short* __restrict__ xg,
    const unsigned short* __restrict__ wP,
    const int* __restrict__ list, const float* __restrict__ wl,
    const int4* __restrict__ table,
    float* __restrict__ out, const int slot)
{
  extern __shared__ char smem[];
  char* wb  = smem;             // 2 x 24576B weight chunk buffers (first 32KB = x staging)
  char* pwb = smem + 49152;     // 4 quarters x 2304B P scratch (72B row stride)
  const int4 tb = table[slot * ENTRIES + blockIdx.x];
  const int e = tb.x, rbeg = tb.y, rcnt = tb.z, n = tb.w;
  if (rcnt == 0) return;
  const int* lst = list + slot * PADN + rbeg;
  const float* wls = wl + slot * PADN + rbeg;
  const int tid = threadIdx.x;
  const int wid = tid >> 6, lane = tid & 63;
  const int lr = lane & 15, lq = lane >> 4;
  const int tq = wid >> 1, ch = wid & 1;   // token-quarter, col-half
  char* pq = pwb + tq * 2304;
  const f32x4 z4 = {0.f, 0.f, 0.f, 0.f};

  const unsigned short* wsrc = wP + (size_t)(e * NHEAD + n) * (12 * 24 * 512);
  const unsigned short* xpan = xg + ((size_t)n * PADN + rbeg) * 128;  // rbeg 128-aligned

  // ---- stage x tile (32KB contiguous, pre-swizzled) into LDS via DMA ----
  #pragma unroll
  for (int i = 0; i < 4; ++i)
    dma16(xpan + (size_t)wid * 2048 + i * 512 + lane * 8, wb + wid * 4096 + i * 1024);
  asm volatile("s_waitcnt vmcnt(0)" ::: "memory");
  __builtin_amdgcn_s_barrier();

  // ---- A-frags: wave's 32 token rows x 4 k-steps -> regs ----
  short8 a[2][4];
  #pragma unroll
  for (int mi = 0; mi < 2; ++mi) {
    int row = tq * 32 + mi * 16 + lr;
    #pragma unroll
    for (int kk = 0; kk < 4; ++kk)
      a[mi][kk] = *reinterpret_cast<const short8*>(
          wb + row * 256 + ((kk * 64 + lq * 16) ^ ((row & 7) << 4)));
  }
  asm volatile("s_waitcnt lgkmcnt(0)" ::: "memory");
  __builtin_amdgcn_sched_barrier(0);
  __builtin_amdgcn_s_barrier();     // all reads done before weight DMA overwrites

  f32x4 acc[2][4];    // out rows (2 mi) x 4 d-col-tiles (persistent)
  #pragma unroll
  for (int mi = 0; mi < 2; ++mi)
    #pragma unroll
    for (int ct = 0; ct < 4; ++ct) acc[mi][ct] = z4;

  // prologue: DMA weight chunk 0 -> buf 0 (3 segs/wave)
  #pragma unroll
  for (int i = 0; i < 3; ++i) {
    int seg = wid * 3 + i;
    dma16(wsrc + (size_t)seg * 512 + lane * 8, wb + seg * 1024);
  }

  #pragma unroll
  for (int c = 0; c < 12; ++c) {
    const int p = c & 1;
    char* wbp = wb + p * 24576;

    // barrier A: all waves done reading buf[p^1] (chunk c-1) -> free for DMA
    asm volatile("s_waitcnt lgkmcnt(0)" ::: "memory");
    __builtin_amdgcn_s_barrier();
    __builtin_amdgcn_sched_barrier(0);

    if (c < 11) {
      char* wbn = wb + (p ^ 1) * 24576;
      #pragma unroll
      for (int i = 0; i < 3; ++i) {
        int seg = wid * 3 + i;
        dma16(wsrc + ((size_t)(c + 1) * 24 + seg) * 512 + lane * 8, wbn + seg * 1024);
      }
      asm volatile("s_waitcnt vmcnt(3)" ::: "memory");  // chunk c landed; c+1 in flight
    } else {
      asm volatile("s_waitcnt vmcnt(0)" ::: "memory");
    }
    // barrier B: everyone's chunk-c DMA landed
    __builtin_amdgcn_s_barrier();
    __builtin_amdgcn_sched_barrier(0);

    // ---- stage 1: ctg = 2c+ch: 16 MFMA (2 mi x 4 kk x {W1,Wg}), silu, P ----
    {
      f32x4 ah[2], ag[2];
      ah[0] = ah[1] = z4; ag[0] = ag[1] = z4;
      #pragma unroll
      for (int kk = 0; kk < 4; ++kk) {
        short8 b1 = *reinterpret_cast<const short8*>(wbp + (kk * 2 + ch) * 1024 + lane * 16);
        short8 bg = *reinterpret_cast<const short8*>(wbp + 8192 + (kk * 2 + ch) * 1024 + lane * 16);
        #pragma unroll
        for (int mi = 0; mi < 2; ++mi) {
          ah[mi] = __builtin_amdgcn_mfma_f32_16x16x32_bf16(a[mi][kk], b1, ah[mi], 0, 0, 0);
          ag[mi] = __builtin_amdgcn_mfma_f32_16x16x32_bf16(a[mi][kk], bg, ag[mi], 0, 0, 0);
        }
      }
      #pragma unroll
      for (int mi = 0; mi < 2; ++mi)
        #pragma unroll
        for (int r = 0; r < 4; ++r) {
          float h1 = ah[mi][r], g = ag[mi][r];
          float val = h1 * g * __builtin_amdgcn_rcpf(1.f + __expf(-g));  // silu
          int rowq = mi * 16 + lq * 4 + r;       // row within quarter (0..31)
          int h = ch * 16 + lr;                  // h within chunk (0..31)
          *reinterpret_cast<unsigned short*>(pq + rowq * 72 + h * 2) = f2bf(val);
        }
    }

    // barrier C: both col-half waves' P writes visible to the quarter
    asm volatile("s_waitcnt lgkmcnt(0)" ::: "memory");
    __builtin_amdgcn_s_barrier();
    __builtin_amdgcn_sched_barrier(0);

    // ---- stage 2: acc += P(32h) @ W2 slice; wave owns d-half ch (4 cts) ----
    {
      short8 a2[2];
      #pragma unroll
      for (int mi = 0; mi < 2; ++mi)
        a2[mi] = *reinterpret_cast<const short8*>(pq + (mi * 16 + lr) * 72 + lq * 16);
      #pragma unroll
      for (int ct = 0; ct < 4; ++ct) {
        short8 b = *reinterpret_cast<const short8*>(wbp + (16 + ch * 4 + ct) * 1024 + lane * 16);
        acc[0][ct] = __builtin_amdgcn_mfma_f32_16x16x32_bf16(a2[0], b, acc[0][ct], 0, 0, 0);
        acc[1][ct] = __builtin_amdgcn_mfma_f32_16x16x32_bf16(a2[1], b, acc[1][ct], 0, 0, 0);
      }
    }
  }

  // ---- epilogue: scale by routing weight, store/accumulate ----
  #pragma unroll
  for (int mi = 0; mi < 2; ++mi)
    #pragma unroll
    for (int r = 0; r < 4; ++r) {
      int row = tq * 32 + mi * 16 + lq * 4 + r;
      if (row < rcnt) {
        int tok = lst[row];
        float wt = wls[row];
        float* op = out + ((size_t)tok * NHEAD + n) * DDIM;
        #pragma unroll
        for (int ct = 0; ct < 4; ++ct) {
          int col = (ch * 4 + ct) * 16 + lr;
          float v = acc[mi][ct][r] * wt;
          if (slot == 0) op[col] = v;   // pass 0: every token exactly once
          else          op[col] += v;   // pass 1: unique writer, after pass 0
        }
      }
    }
}

extern "C" void kernel_launch(void* const* d_in, const int* in_sizes, int n_in,
                              void* d_out, int out_size, void* d_ws, size_t ws_size,
                              hipStream_t stream) {
  const float* x  = (const float*)d_in[0];
  const float* rw = (const float*)d_in[1];
  const float* w1 = (const float*)d_in[2];
  const float* wg = (const float*)d_in[3];
  const float* w2 = (const float*)d_in[4];
  float* out = (float*)d_out;
  char* ws = (char*)d_ws;

  unsigned short* wP = (unsigned short*)(ws + OFF_WP);
  Routing* routing = (Routing*)(ws + OFF_ROUT);
  int* cnt = (int*)(ws + OFF_CNT);
  int* cur = cnt + 16;
  int4* table = (int4*)(ws + OFF_TAB);
  int* list = (int*)(ws + OFF_LIST);
  int* posmap = (int*)(ws + OFF_POS);
  float* wl = (float*)(ws + OFF_WL);
  unsigned short* xg0 = (unsigned short*)(ws + OFF_XG);

  const bool dual = (ws_size >= OFF_XG + 2 * XG_SLOT);
  unsigned short* xg1 = dual ? (unsigned short*)(ws + OFF_XG + XG_SLOT) : xg0;

  convA_kernel<<<dim3(4, 128, 2), 256, 0, stream>>>(w1, wg, wP);
  convB_kernel<<<dim3(12, 128, 1), 256, 0, stream>>>(w2, wP);
  router_kernel<<<512, 256, 0, stream>>>(x, rw, routing);
  count_kernel<<<16, 256, 0, stream>>>(routing, cnt);
  build_kernel<<<1, 256, 0, stream>>>(cnt, cur, table, list);
  compact_kernel<<<16, 256, 0, stream>>>(routing, cur, list, wl, posmap);

  if (dual) {
    gather_kernel<<<256, 256, 0, stream>>>(x, posmap, xg0, xg1, 0);
    expert_kernel<<<ENTRIES, 512, 58368, stream>>>(xg0, wP, list, wl, table, out, 0);
    expert_kernel<<<ENTRIES, 512, 58368, stream>>>(xg1, wP, list, wl, table, out, 1);
  } else {
    gather_kernel<<<256, 256, 0, stream>>>(x, posmap, xg0, xg0, 1);
    expert_kernel<<<ENTRIES, 512, 58368, stream>>>(xg0, wP, list, wl, table, out, 0);
    gather_kernel<<<256, 256, 0, stream>>>(x, posmap, xg0, xg0, 2);
    expert_kernel<<<ENTRIES, 512, 58368, stream>>>(xg0, wP, list, wl, table, out, 1);
  }
}